// Round 14
// baseline (259.374 us; speedup 1.0000x reference)
//
#include <hip/hip_runtime.h>

// ============================================================================
// InteractionLayer v14 = v11 + unified 4-slot K/V register ring (depth-2
// prefetch, register-neutral). Stagger dropped (r13: clean null).
// All MFMA = v_mfma_f32_32x32x16_bf16.
//   a-operand: lane l holds A[row=l&31][k=(l>>5)*8 + j], j=0..7 (k-contiguous)
//   b-operand: lane l holds B[k=(l>>5)*8 + j][col=l&31] (= B^T row-major)
//   C/D:       col=lane&31, row=(reg&3)+8*(reg>>2)+4*(lane>>5)   [m74/m101]
// v14 attn: kfb[2][8]+vfb[2][8] -> fb[4][8] (same 128 VGPR; K and V
// time-share the ring, liveness law respected). Issue->consume distance
// 2 g-steps (~270 cyc >= L2 latency ~200). Handoffs: S g6/g7 issue V-primes
// for PV g0/g1 (in flight across softmax+B_RAW); PV g6/g7 issue K-primes for
// the next tile (in flight across B_WAR). All slot indices compile-time.
// Liveness law (r4/r5/r12): 128 acc regs + 128 VGPR buffers = the 2-wave/SIMD
// cap; never exceed 4 live slots.
// ============================================================================

typedef __attribute__((ext_vector_type(8)))  short short8;
typedef __attribute__((ext_vector_type(16))) float f32x16;
typedef __attribute__((ext_vector_type(4)))  float float4v;

__device__ __forceinline__ short f2bf(float x){
  unsigned int u = __float_as_uint(x);
  u = (u + 0x7FFFu + ((u >> 16) & 1u)) >> 16;   // RNE f32->bf16 (finite inputs)
  return (short)u;
}

__device__ __forceinline__ unsigned cvt_pk_bf16(float a, float b){
  unsigned r;                                    // D.lo=bf16(a), D.hi=bf16(b), RNE
  asm("v_cvt_pk_bf16_f32 %0, %1, %2" : "=v"(r) : "v"(a), "v"(b));
  return r;
}

__device__ __forceinline__ float fast_exp2(float x){
  float r; asm("v_exp_f32 %0, %1" : "=v"(r) : "v"(x)); return r;
}

// LDS-fence barrier that does NOT drain vmcnt (prefetches stay in flight)
__device__ __forceinline__ void bar_lgkm(){
  asm volatile("s_waitcnt lgkmcnt(0)" ::: "memory");
  __builtin_amdgcn_s_barrier();
}

typedef const __attribute__((address_space(1))) unsigned int guint_t;
typedef __attribute__((address_space(3))) unsigned int luint_t;
__device__ __forceinline__ void gl_lds16(const void* g, void* l){
  __builtin_amdgcn_global_load_lds((guint_t*)g, (luint_t*)l, 16, 0, 0);
}

// ---------------- fused weight transpose + bf16 convert ----------------
__global__ __launch_bounds__(256) void transpose_cvt_fused(
    const float* __restrict__ Wq, const float* __restrict__ Wk,
    const float* __restrict__ Wv,
    short* __restrict__ WqT, short* __restrict__ WkT, short* __restrict__ WvT)
{
  int idx = blockIdx.x * 256 + threadIdx.x;
  if (idx < 524288){
    int n = idx & 511, k = idx >> 9;
    WqT[(n<<10) + k] = f2bf(Wq[idx]);
  } else if (idx < 786432){
    int j = idx - 524288; int n = j & 511, k = j >> 9;
    WkT[(n<<9) + k] = f2bf(Wk[j]);
  } else {
    int j = idx - 786432; int n = j & 511, k = j >> 9;
    WvT[(n<<9) + k] = f2bf(Wv[j]);
  }
}

// ---------------- fused projection GEMM (round-11, unchanged) ----------------
__global__ __launch_bounds__(256, 2) void proj_gemm_fused(
    const float* __restrict__ Aq, const float* __restrict__ Ak,
    const float* __restrict__ Av,
    const short* __restrict__ Wq, const short* __restrict__ Wk,
    const short* __restrict__ Wv,
    const float* __restrict__ bq, const float* __restrict__ bk,
    const float* __restrict__ bv,
    short* __restrict__ Cq, short* __restrict__ Ck, short* __restrict__ Cv,
    float scale)
{
  __shared__ char As[16384];
  __shared__ char Bs[16384];
  const int pz = blockIdx.z;
  const float* A    = (pz==0) ? Aq : (pz==1) ? Ak : Av;
  const short* WT   = (pz==0) ? Wq : (pz==1) ? Wk : Wv;
  const float* bias = (pz==0) ? bq : (pz==1) ? bk : bv;
  short* C          = (pz==0) ? Cq : (pz==1) ? Ck : Cv;
  const int K       = (pz==0) ? 1024 : 512;
  const float alpha = (pz==0) ? scale : 1.0f;

  const int tid = threadIdx.x;
  const int wid = tid >> 6, lane = tid & 63;
  const int lo = lane & 31, hi = lane >> 5;
  const int wm = wid >> 1, wn = wid & 1;
  const int bm = blockIdx.x, bn = blockIdx.y;
  const char* WTb = (const char*)WT;

  f32x16 acc[2][2];
  #pragma unroll
  for (int i=0;i<2;i++)
    #pragma unroll
    for (int j=0;j<2;j++)
      #pragma unroll
      for (int r=0;r<16;r++) acc[i][j][r] = 0.0f;

  const int srow = tid >> 3, sslot = tid & 7;
  const int aswz = (sslot*16) ^ ((srow&7)<<4);
  for (int k0 = 0; k0 < K; k0 += 64) {
    #pragma unroll
    for (int i=0;i<4;i++){
      const int rb0 = wid*32 + i*8;
      const int rr = lane >> 3;                  // 0..7
      const void* src = WTb + ((size_t)(bn*128 + rb0 + rr)*K + k0)*2
                        + (((lane&7)*16) ^ (rr<<4));
      gl_lds16(src, Bs + rb0*128);
    }
    #pragma unroll
    for (int i=0;i<4;i++){
      const int row = srow + 32*i;
      const float4v* src = (const float4v*)&A[(size_t)(bm*128+row)*K + k0 + sslot*8];
      float4v f0 = src[0], f1 = src[1];
      uint4 u;
      u.x = cvt_pk_bf16(f0[0], f0[1]);
      u.y = cvt_pk_bf16(f0[2], f0[3]);
      u.z = cvt_pk_bf16(f1[0], f1[1]);
      u.w = cvt_pk_bf16(f1[2], f1[3]);
      *(uint4*)(As + row*128 + aswz) = u;
    }
    __syncthreads();
    #pragma unroll
    for (int dc=0; dc<4; dc++){
      short8 af[2], bfr[2];
      #pragma unroll
      for (int mt=0;mt<2;mt++){
        const int ra = wm*64+mt*32+lo;
        af[mt] = *(const short8*)(As + ra*128 + ((dc*32 + hi*16) ^ ((ra&7)<<4)));
      }
      #pragma unroll
      for (int nt=0;nt<2;nt++){
        const int rb = wn*64+nt*32+lo;
        bfr[nt] = *(const short8*)(Bs + rb*128 + ((dc*32 + hi*16) ^ ((rb&7)<<4)));
      }
      #pragma unroll
      for (int mt=0;mt<2;mt++)
        #pragma unroll
        for (int nt=0;nt<2;nt++)
          acc[mt][nt] = __builtin_amdgcn_mfma_f32_32x32x16_bf16(af[mt], bfr[nt], acc[mt][nt], 0, 0, 0);
    }
    __syncthreads();
  }

  char* Cb = (char*)C;
  #pragma unroll
  for (int nt=0;nt<2;nt++){
    const int col = bn*128 + wn*64 + nt*32 + lo;
    const float bv2 = bias[col];
    #pragma unroll
    for (int mt=0;mt<2;mt++){
      const int grow0 = bm*128 + wm*64 + mt*32;
      if (pz == 0){            // Q attn-layout (frag-tiled per 64-row block)
        #pragma unroll
        for (int r=0;r<16;r++){
          const int t = grow0 + (r&3) + 8*(r>>2) + 4*hi;
          const int d = col;
          const float val = (acc[mt][nt][r] + bv2) * alpha;
          size_t addr = (size_t)(t>>6)*65536
                      + (size_t)((d>>5)*4 + ((d>>4)&1)*2 + ((d>>3)&1))*1024
                      + (size_t)(t&63)*16 + (d&7)*2;
          *(short*)(Cb + addr) = f2bf(val);
        }
      } else if (pz == 1){     // K band-major frag-tiled
        #pragma unroll
        for (int r=0;r<16;r++){
          const int t = grow0 + (r&3) + 8*(r>>2) + 4*hi;
          const int d = col;
          const float val = acc[mt][nt][r] + bv2;
          size_t addr = (size_t)(t>>9)*524288 + (size_t)((t>>5)&15)*32768
                      + (size_t)((d>>5)*2 + ((d>>4)&1))*1024
                      + (size_t)((t&31) + 32*((d>>3)&1))*16 + (d&7)*2;
          *(short*)(Cb + addr) = f2bf(val);
        }
      } else {                 // V band-major frag-tiled
        #pragma unroll
        for (int r=0;r<16;r++){
          const int t = grow0 + (r&3) + 8*(r>>2) + 4*hi;
          const int d = col;
          const float val = acc[mt][nt][r] + bv2;
          size_t addr = (size_t)(t>>9)*524288 + (size_t)(d>>6)*65536
                      + (size_t)(((d>>5)&1)*32 + ((t>>4)&31))*1024
                      + (size_t)((d&31) + 32*((t>>3)&1))*16 + (t&7)*2;
          *(short*)(Cb + addr) = f2bf(val);
        }
      }
    }
  }
}

// ---------------- fused flash attention v14: unified depth-2 ring ----------
#define PLDS  65536
#define LSUMO 131072
#define ALDS  133120

__global__ __launch_bounds__(512, 2) void attn_fwd(
    const char* __restrict__ Qg, const char* __restrict__ Kf,
    const char* __restrict__ Vf, float* __restrict__ out)
{
  extern __shared__ char smem[];
  float* lsum_lds = (float*)(smem + LSUMO);

  const int tid = threadIdx.x;
  const int w = tid >> 6, lane = tid & 63;
  const int lo = lane & 31, hi = lane >> 5;
  const int wg = ((blockIdx.x & 7) << 5) + (blockIdx.x >> 3);  // XCD swizzle
  const int b = wg >> 6, qt = wg & 63;
  const size_t qrow0 = ((size_t)b << 12) + (size_t)qt*64;

  // per-lane LDS bases (the ONLY per-lane address math in the hot loop)
  const int qbase  = hi*1024 + lo*16;                 // Q reads
  const int prbase = PLDS + hi*1024 + lo*16;          // P reads
  const int pwbase = PLDS + (w<<13) + lo*16 + hi*8;   // P writes

  // ---- prologue: stage Q (already in attn layout) -- contiguous gl_lds ----
  {
    const char* qsrc = Qg + (size_t)wg*65536;
    #pragma unroll
    for (int i=0;i<8;i++)
      gl_lds16(qsrc + (w*8+i)*1024 + lane*16, smem + (w*8+i)*1024);
  }

  f32x16 oacc[2][2];
  #pragma unroll
  for (int i=0;i<2;i++)
    #pragma unroll
    for (int j=0;j<2;j++)
      #pragma unroll
      for (int r=0;r<16;r++) oacc[i][j][r]=0.f;
  float ls[2] = {0.f, 0.f};

  const char* Kb = Kf + (size_t)b*4194304;
  const char* Vb = Vf + (size_t)b*4194304;
  short8 fb[4][8];   // unified K/V ring: 4 slots x 8 frags = 128 VGPR

  // prime fb[0]=K(tile0,g0), fb[1]=K(tile0,g1); drained by prologue barrier
  {
    const char* k0 = Kb + (size_t)(2*w)*32768 + (size_t)lane*16;
    #pragma unroll
    for (int kvsub=0;kvsub<2;kvsub++)
      #pragma unroll
      for (int dc2=0;dc2<2;dc2++)
        #pragma unroll
        for (int ks=0;ks<2;ks++){
          fb[0][kvsub*4+dc2*2+ks] = *(const short8*)(k0
              + (size_t)kvsub*32768 + dc2*2048 + ks*1024);
          fb[1][kvsub*4+dc2*2+ks] = *(const short8*)(k0
              + (size_t)kvsub*32768 + (2+dc2)*2048 + ks*1024);
        }
  }
  __syncthreads();   // full drain: Q staging (gl_lds) must be LDS-visible

  for (int kvt = 0; kvt < 8; kvt++) {
    const bool last = (kvt == 7);
    const char* kbaseC = Kb + (size_t)kvt*524288 + (size_t)(2*w)*32768 + (size_t)lane*16;
    const char* kbaseN = Kb + (size_t)((kvt+1)&7)*524288 + (size_t)(2*w)*32768 + (size_t)lane*16;
    const char* vbase  = Vb + (size_t)kvt*524288 + (size_t)(w)*65536 + (size_t)lane*16;

    // ================= S phase: sacc[kvsub][qs] = K_band x Q =================
    f32x16 sacc[2][2];
    #pragma unroll
    for (int i=0;i<2;i++)
      #pragma unroll
      for (int j=0;j<2;j++)
        #pragma unroll
        for (int r=0;r<16;r++) sacc[i][j][r]=0.f;

    #pragma unroll
    for (int g=0; g<8; g++){
      if (g < 6){              // issue K(g+2) -> slot (g+2)&3  (distance 2)
        #pragma unroll
        for (int kvsub=0;kvsub<2;kvsub++)
          #pragma unroll
          for (int dc2=0;dc2<2;dc2++)
            #pragma unroll
            for (int ks=0;ks<2;ks++)
              fb[(g+2)&3][kvsub*4+dc2*2+ks] = *(const short8*)(kbaseC
                  + (size_t)kvsub*32768 + (2*(g+2)+dc2)*2048 + ks*1024);
      } else {                 // g=6/7: issue V-primes for PV g0/g1 -> fb[0]/fb[1]
        const int pg = g - 6;
        #pragma unroll
        for (int dsub=0;dsub<2;dsub++)
          #pragma unroll
          for (int ts=0;ts<4;ts++)
            fb[pg][dsub*4+ts] = *(const short8*)(vbase
                + (size_t)dsub*32768 + (pg*4+ts)*1024);
      }
      __builtin_amdgcn_s_setprio(1);
      #pragma unroll
      for (int dc2=0;dc2<2;dc2++)
        #pragma unroll
        for (int ks=0;ks<2;ks++){
          const int dch = 2*g + dc2;
          short8 qf[2];
          #pragma unroll
          for (int qs=0;qs<2;qs++)
            qf[qs] = *(const short8*)(smem + qbase + dch*4096 + ks*2048 + qs*512);
          #pragma unroll
          for (int kvsub=0;kvsub<2;kvsub++)
            #pragma unroll
            for (int qs=0;qs<2;qs++)
              sacc[kvsub][qs] = __builtin_amdgcn_mfma_f32_32x32x16_bf16(
                  fb[g&3][kvsub*4+dc2*2+ks], qf[qs], sacc[kvsub][qs], 0, 0, 0);
        }
      __builtin_amdgcn_s_setprio(0);
    }

    // ================= softmax: p = 2^s (raw v_exp_f32; scale cancels) =====
    #pragma unroll
    for (int kvsub=0;kvsub<2;kvsub++)
      #pragma unroll
      for (int qs=0;qs<2;qs++){
        #pragma unroll
        for (int g4=0; g4<4; g4++){
          float p0 = fast_exp2(sacc[kvsub][qs][4*g4+0]);
          float p1 = fast_exp2(sacc[kvsub][qs][4*g4+1]);
          float p2 = fast_exp2(sacc[kvsub][qs][4*g4+2]);
          float p3 = fast_exp2(sacc[kvsub][qs][4*g4+3]);
          ls[qs] += (p0 + p1) + (p2 + p3);
          uint2 pv;
          pv.x = cvt_pk_bf16(p0, p1);
          pv.y = cvt_pk_bf16(p2, p3);
          *(uint2*)(smem + pwbase + kvsub*4096 + g4*1024 + qs*512) = pv;
        }
      }
    bar_lgkm();                                        // B_RAW: P visible (vmcnt live)

    // ================= PV phase: oacc[dsub][qs] += V^T_band x P^ ============
    #pragma unroll
    for (int g=0; g<8; g++){
      if (g < 6){              // issue V(g+2) -> slot (g+2)&3
        #pragma unroll
        for (int dsub=0;dsub<2;dsub++)
          #pragma unroll
          for (int ts=0;ts<4;ts++)
            fb[(g+2)&3][dsub*4+ts] = *(const short8*)(vbase
                + (size_t)dsub*32768 + ((g+2)*4+ts)*1024);
      } else if (!last){       // g=6/7: issue K-primes for next tile g0/g1
        const int pg = g - 6;
        #pragma unroll
        for (int kvsub=0;kvsub<2;kvsub++)
          #pragma unroll
          for (int dc2=0;dc2<2;dc2++)
            #pragma unroll
            for (int ks=0;ks<2;ks++)
              fb[pg][kvsub*4+dc2*2+ks] = *(const short8*)(kbaseN
                  + (size_t)kvsub*32768 + (2*pg+dc2)*2048 + ks*1024);
      }
      __builtin_amdgcn_s_setprio(1);
      #pragma unroll
      for (int ts=0; ts<4; ts++){
        const int tst = g*4 + ts;
        short8 pf[2];
        #pragma unroll
        for (int qs=0;qs<2;qs++)
          pf[qs] = *(const short8*)(smem + prbase + tst*2048 + qs*512);
        #pragma unroll
        for (int dsub=0;dsub<2;dsub++)
          #pragma unroll
          for (int qs=0;qs<2;qs++)
            oacc[dsub][qs] = __builtin_amdgcn_mfma_f32_32x32x16_bf16(
                fb[g&3][dsub*4+ts], pf[qs], oacc[dsub][qs], 0, 0, 0);
      }
      __builtin_amdgcn_s_setprio(0);
    }
    bar_lgkm();                                        // B_WAR: P reusable (vmcnt live)
  }

  // ---- final cross-wave l reduction (once) ----
  ls[0] += __shfl_xor(ls[0], 32);
  ls[1] += __shfl_xor(ls[1], 32);
  if (hi == 0){
    lsum_lds[w*64 + lo]      = ls[0];
    lsum_lds[w*64 + 32 + lo] = ls[1];
  }
  __syncthreads();

  // ---- epilogue: out[q][d] = O^T[d][q] / l ----
  #pragma unroll
  for (int qs=0;qs<2;qs++){
    float l_tot = 0.f;
    #pragma unroll
    for (int wv=0;wv<8;wv++) l_tot += lsum_lds[wv*64 + qs*32 + lo];
    const float inv = 1.0f / l_tot;
    const size_t row = qrow0 + qs*32 + lo;
    #pragma unroll
    for (int dsub=0;dsub<2;dsub++){
      #pragma unroll
      for (int g4=0;g4<4;g4++){
        float4v ov;
        #pragma unroll
        for (int j=0;j<4;j++) ov[j] = oacc[dsub][qs][4*g4+j]*inv;
        *(float4v*)&out[row*512 + w*64 + dsub*32 + g4*8 + hi*4] = ov;
      }
    }
  }
}

extern "C" void kernel_launch(void* const* d_in, const int* in_sizes, int n_in,
                              void* d_out, int out_size, void* d_ws, size_t ws_size,
                              hipStream_t stream)
{
  const float* m_states = (const float*)d_in[0];
  const float* f_k      = (const float*)d_in[1];
  const float* f_v      = (const float*)d_in[2];
  const float* W_q      = (const float*)d_in[3];
  const float* b_q      = (const float*)d_in[4];
  const float* W_k      = (const float*)d_in[5];
  const float* b_k      = (const float*)d_in[6];
  const float* W_v      = (const float*)d_in[7];
  const float* b_v      = (const float*)d_in[8];
  float* out = (float*)d_out;

  // workspace: WqT 1MB | WkT 0.5MB | WvT 0.5MB | Q 16MB | Kfrag 16MB | Vfrag 16MB
  char* ws = (char*)d_ws;
  short* WqT = (short*)(ws);
  short* WkT = (short*)(ws + 1048576);
  short* WvT = (short*)(ws + 1048576 + 524288);
  short* Qb  = (short*)(ws + 2097152);
  short* Kfr = Qb + (size_t)16384*512;
  short* Vfr = Kfr + (size_t)16384*512;

  transpose_cvt_fused<<<4096, 256, 0, stream>>>(W_q, W_k, W_v, WqT, WkT, WvT);

  // 1/sqrt(512) * log2(e): softmax runs in base-2 domain
  const float scale = 0.044194173824159216f * 1.4426950408889634f;
  proj_gemm_fused<<<dim3(128,4,3), 256, 0, stream>>>(
      m_states, f_k, f_v, WqT, WkT, WvT, b_q, b_k, b_v,
      Qb, Kfr, Vfr, scale);

  attn_fwd<<<256, 512, ALDS, stream>>>((const char*)Qb, (const char*)Kfr,
                                       (const char*)Vfr, out);
}

// Round 15
// 196.104 us; speedup vs baseline: 1.3226x; 1.3226x over previous
//
#include <hip/hip_runtime.h>

// ============================================================================
// InteractionLayer v15: attn = v11 VERBATIM (frozen: 129.5us, MfmaUtil 49.5%;
// stagger=null r13, reorder/ring/fusion=spill r12/r14/r4/r5 -- the 2-wave
// register wall is binding). Projections redesigned: full-width blocks.
//   proj: 64x512 tile, 256 thr / 4 waves, acc[2][4] (128 AGPR), Bs = 512 W
//   cols x 64 k (64KB, gl_lds), As 8KB -> 72KB LDS, 2 blocks/CU.
//   A read EXACTLY ONCE from HBM (was 4x L3 re-read); W re-reads L2-resident.
//   Epilogue layout formulas (t,d) byte-identical to v11.
// All MFMA = v_mfma_f32_32x32x16_bf16.
//   a-operand: lane l holds A[row=l&31][k=(l>>5)*8 + j], j=0..7 (k-contiguous)
//   b-operand: lane l holds B[k=(l>>5)*8 + j][col=l&31] (= B^T row-major)
//   C/D:       col=lane&31, row=(reg&3)+8*(reg>>2)+4*(lane>>5)   [m74/m101]
// ============================================================================

typedef __attribute__((ext_vector_type(8)))  short short8;
typedef __attribute__((ext_vector_type(16))) float f32x16;
typedef __attribute__((ext_vector_type(4)))  float float4v;

__device__ __forceinline__ short f2bf(float x){
  unsigned int u = __float_as_uint(x);
  u = (u + 0x7FFFu + ((u >> 16) & 1u)) >> 16;   // RNE f32->bf16 (finite inputs)
  return (short)u;
}

__device__ __forceinline__ unsigned cvt_pk_bf16(float a, float b){
  unsigned r;                                    // D.lo=bf16(a), D.hi=bf16(b), RNE
  asm("v_cvt_pk_bf16_f32 %0, %1, %2" : "=v"(r) : "v"(a), "v"(b));
  return r;
}

__device__ __forceinline__ float fast_exp2(float x){
  float r; asm("v_exp_f32 %0, %1" : "=v"(r) : "v"(x)); return r;
}

// LDS-fence barrier that does NOT drain vmcnt (prefetches stay in flight)
__device__ __forceinline__ void bar_lgkm(){
  asm volatile("s_waitcnt lgkmcnt(0)" ::: "memory");
  __builtin_amdgcn_s_barrier();
}

typedef const __attribute__((address_space(1))) unsigned int guint_t;
typedef __attribute__((address_space(3))) unsigned int luint_t;
__device__ __forceinline__ void gl_lds16(const void* g, void* l){
  __builtin_amdgcn_global_load_lds((guint_t*)g, (luint_t*)l, 16, 0, 0);
}

// ---------------- fused weight transpose + bf16 convert ----------------
__global__ __launch_bounds__(256) void transpose_cvt_fused(
    const float* __restrict__ Wq, const float* __restrict__ Wk,
    const float* __restrict__ Wv,
    short* __restrict__ WqT, short* __restrict__ WkT, short* __restrict__ WvT)
{
  int idx = blockIdx.x * 256 + threadIdx.x;
  if (idx < 524288){
    int n = idx & 511, k = idx >> 9;
    WqT[(n<<10) + k] = f2bf(Wq[idx]);
  } else if (idx < 786432){
    int j = idx - 524288; int n = j & 511, k = j >> 9;
    WkT[(n<<9) + k] = f2bf(Wk[j]);
  } else {
    int j = idx - 786432; int n = j & 511, k = j >> 9;
    WvT[(n<<9) + k] = f2bf(Wv[j]);
  }
}

// ---------------- fused projection GEMM v15: 64x512 full-width blocks ------
// grid (256, 3): blockIdx.x = bm (64-row panel), blockIdx.y = pz (Q/K/V).
// Wave wid (0..3) owns cols [wid*128, wid*128+128): acc[mt=2][nt=4].
__global__ __launch_bounds__(256, 2) void proj_gemm_fused(
    const float* __restrict__ Aq, const float* __restrict__ Ak,
    const float* __restrict__ Av,
    const short* __restrict__ Wq, const short* __restrict__ Wk,
    const short* __restrict__ Wv,
    const float* __restrict__ bq, const float* __restrict__ bk,
    const float* __restrict__ bv,
    short* __restrict__ Cq, short* __restrict__ Ck, short* __restrict__ Cv,
    float scale)
{
  __shared__ char As[8192];     // [64 rows][64 k] bf16, 128B/row, XOR swizzle
  __shared__ char Bs[65536];    // [512 cols][64 k] bf16 (W^T rows), 128B/row
  const int pz = blockIdx.y;
  const float* A    = (pz==0) ? Aq : (pz==1) ? Ak : Av;
  const short* WT   = (pz==0) ? Wq : (pz==1) ? Wk : Wv;
  const float* bias = (pz==0) ? bq : (pz==1) ? bk : bv;
  short* C          = (pz==0) ? Cq : (pz==1) ? Ck : Cv;
  const int K       = (pz==0) ? 1024 : 512;
  const float alpha = (pz==0) ? scale : 1.0f;

  const int tid = threadIdx.x;
  const int wid = tid >> 6, lane = tid & 63;
  const int lo = lane & 31, hi = lane >> 5;
  const int bm = blockIdx.x;
  const char* WTb = (const char*)WT;

  f32x16 acc[2][4];
  #pragma unroll
  for (int i=0;i<2;i++)
    #pragma unroll
    for (int j=0;j<4;j++)
      #pragma unroll
      for (int r=0;r<16;r++) acc[i][j][r] = 0.0f;

  const int srow = tid >> 2, sslot = tid & 3;   // A: 64 rows x 4 thr/row
  for (int k0 = 0; k0 < K; k0 += 64) {
    // ---- B staging: all 512 W-cols x 64 k; wave stages its own 128 rows ----
    #pragma unroll
    for (int i=0;i<16;i++){
      const int rb0 = wid*128 + i*8;
      const int rr = lane >> 3;                  // 0..7
      const void* src = WTb + ((size_t)(rb0 + rr)*K + k0)*2
                        + (((lane&7)*16) ^ (rr<<4));
      gl_lds16(src, Bs + rb0*128);
    }
    // ---- A staging: 64 rows; thread reads 16 f32 -> 32B bf16, swizzled ----
    {
      const float4v* src = (const float4v*)&A[(size_t)(bm*64+srow)*K + k0 + sslot*16];
      float4v f0 = src[0], f1 = src[1], f2 = src[2], f3 = src[3];
      uint4 u0, u1;
      u0.x = cvt_pk_bf16(f0[0], f0[1]);
      u0.y = cvt_pk_bf16(f0[2], f0[3]);
      u0.z = cvt_pk_bf16(f1[0], f1[1]);
      u0.w = cvt_pk_bf16(f1[2], f1[3]);
      u1.x = cvt_pk_bf16(f2[0], f2[1]);
      u1.y = cvt_pk_bf16(f2[2], f2[3]);
      u1.z = cvt_pk_bf16(f3[0], f3[1]);
      u1.w = cvt_pk_bf16(f3[2], f3[3]);
      const int swz = (srow&7)<<4;
      *(uint4*)(As + srow*128 + ((sslot*32)      ^ swz)) = u0;
      *(uint4*)(As + srow*128 + ((sslot*32 + 16) ^ swz)) = u1;
    }
    __syncthreads();
    #pragma unroll
    for (int dc=0; dc<4; dc++){
      short8 af[2], bfr[4];
      #pragma unroll
      for (int mt=0;mt<2;mt++){
        const int ra = mt*32+lo;
        af[mt] = *(const short8*)(As + ra*128 + ((dc*32 + hi*16) ^ ((ra&7)<<4)));
      }
      #pragma unroll
      for (int nt=0;nt<4;nt++){
        const int rb = wid*128 + nt*32 + lo;
        bfr[nt] = *(const short8*)(Bs + rb*128 + ((dc*32 + hi*16) ^ ((rb&7)<<4)));
      }
      #pragma unroll
      for (int mt=0;mt<2;mt++)
        #pragma unroll
        for (int nt=0;nt<4;nt++)
          acc[mt][nt] = __builtin_amdgcn_mfma_f32_32x32x16_bf16(af[mt], bfr[nt], acc[mt][nt], 0, 0, 0);
    }
    __syncthreads();
  }

  char* Cb = (char*)C;
  #pragma unroll
  for (int nt=0;nt<4;nt++){
    const int col = wid*128 + nt*32 + lo;
    const float bv2 = bias[col];
    #pragma unroll
    for (int mt=0;mt<2;mt++){
      const int grow0 = bm*64 + mt*32;
      if (pz == 0){            // Q attn-layout (frag-tiled per 64-row block)
        #pragma unroll
        for (int r=0;r<16;r++){
          const int t = grow0 + (r&3) + 8*(r>>2) + 4*hi;
          const int d = col;
          const float val = (acc[mt][nt][r] + bv2) * alpha;
          size_t addr = (size_t)(t>>6)*65536
                      + (size_t)((d>>5)*4 + ((d>>4)&1)*2 + ((d>>3)&1))*1024
                      + (size_t)(t&63)*16 + (d&7)*2;
          *(short*)(Cb + addr) = f2bf(val);
        }
      } else if (pz == 1){     // K band-major frag-tiled
        #pragma unroll
        for (int r=0;r<16;r++){
          const int t = grow0 + (r&3) + 8*(r>>2) + 4*hi;
          const int d = col;
          const float val = acc[mt][nt][r] + bv2;
          size_t addr = (size_t)(t>>9)*524288 + (size_t)((t>>5)&15)*32768
                      + (size_t)((d>>5)*2 + ((d>>4)&1))*1024
                      + (size_t)((t&31) + 32*((d>>3)&1))*16 + (d&7)*2;
          *(short*)(Cb + addr) = f2bf(val);
        }
      } else {                 // V band-major frag-tiled
        #pragma unroll
        for (int r=0;r<16;r++){
          const int t = grow0 + (r&3) + 8*(r>>2) + 4*hi;
          const int d = col;
          const float val = acc[mt][nt][r] + bv2;
          size_t addr = (size_t)(t>>9)*524288 + (size_t)(d>>6)*65536
                      + (size_t)(((d>>5)&1)*32 + ((t>>4)&31))*1024
                      + (size_t)((d&31) + 32*((t>>3)&1))*16 + (t&7)*2;
          *(short*)(Cb + addr) = f2bf(val);
        }
      }
    }
  }
}

// ---------------- fused flash attention (v11 VERBATIM, 129.5us) ------------
#define PLDS  65536
#define LSUMO 131072
#define ALDS  133120

__global__ __launch_bounds__(512, 2) void attn_fwd(
    const char* __restrict__ Qg, const char* __restrict__ Kf,
    const char* __restrict__ Vf, float* __restrict__ out)
{
  extern __shared__ char smem[];
  float* lsum_lds = (float*)(smem + LSUMO);

  const int tid = threadIdx.x;
  const int w = tid >> 6, lane = tid & 63;
  const int lo = lane & 31, hi = lane >> 5;
  const int wg = ((blockIdx.x & 7) << 5) + (blockIdx.x >> 3);  // XCD swizzle
  const int b = wg >> 6, qt = wg & 63;
  const size_t qrow0 = ((size_t)b << 12) + (size_t)qt*64;

  // per-lane LDS bases (the ONLY per-lane address math in the hot loop)
  const int qbase  = hi*1024 + lo*16;                 // Q reads
  const int prbase = PLDS + hi*1024 + lo*16;          // P reads
  const int pwbase = PLDS + (w<<13) + lo*16 + hi*8;   // P writes

  // ---- prologue: stage Q (already in attn layout) -- contiguous gl_lds ----
  {
    const char* qsrc = Qg + (size_t)wg*65536;
    #pragma unroll
    for (int i=0;i<8;i++)
      gl_lds16(qsrc + (w*8+i)*1024 + lane*16, smem + (w*8+i)*1024);
  }

  f32x16 oacc[2][2];
  #pragma unroll
  for (int i=0;i<2;i++)
    #pragma unroll
    for (int j=0;j<2;j++)
      #pragma unroll
      for (int r=0;r<16;r++) oacc[i][j][r]=0.f;
  float ls[2] = {0.f, 0.f};

  const char* Kb = Kf + (size_t)b*4194304;
  const char* Vb = Vf + (size_t)b*4194304;
  short8 kfb[2][8], vfb[2][8];

  // prime kfb[0] for tile 0 (drained by the prologue __syncthreads, once)
  {
    const char* kbase0 = Kb + (size_t)(2*w)*32768 + (size_t)lane*16;
    #pragma unroll
    for (int kvsub=0;kvsub<2;kvsub++)
      #pragma unroll
      for (int dc2=0;dc2<2;dc2++)
        #pragma unroll
        for (int ks=0;ks<2;ks++)
          kfb[0][kvsub*4+dc2*2+ks] = *(const short8*)(kbase0
              + (size_t)kvsub*32768 + dc2*2048 + ks*1024);
  }
  __syncthreads();   // full drain: Q staging (gl_lds) must be LDS-visible

  for (int kvt = 0; kvt < 8; kvt++) {
    const bool last = (kvt == 7);
    const char* kbaseC = Kb + (size_t)kvt*524288 + (size_t)(2*w)*32768 + (size_t)lane*16;
    const char* kbaseN = Kb + (size_t)((kvt+1)&7)*524288 + (size_t)(2*w)*32768 + (size_t)lane*16;
    const char* vbase  = Vb + (size_t)kvt*524288 + (size_t)(w)*65536 + (size_t)lane*16;

    // ================= S phase: sacc[kvsub][qs] = K_band x Q =================
    f32x16 sacc[2][2];
    #pragma unroll
    for (int i=0;i<2;i++)
      #pragma unroll
      for (int j=0;j<2;j++)
        #pragma unroll
        for (int r=0;r<16;r++) sacc[i][j][r]=0.f;

    #pragma unroll
    for (int g=0; g<8; g++){
      const int bf = g & 1;
      if (g < 7){
        #pragma unroll
        for (int kvsub=0;kvsub<2;kvsub++)
          #pragma unroll
          for (int dc2=0;dc2<2;dc2++)
            #pragma unroll
            for (int ks=0;ks<2;ks++)
              kfb[bf^1][kvsub*4+dc2*2+ks] = *(const short8*)(kbaseC
                  + (size_t)kvsub*32768 + (2*(g+1)+dc2)*2048 + ks*1024);
      }
      __builtin_amdgcn_s_setprio(1);
      #pragma unroll
      for (int dc2=0;dc2<2;dc2++)
        #pragma unroll
        for (int ks=0;ks<2;ks++){
          const int dch = 2*g + dc2;
          short8 qf[2];
          #pragma unroll
          for (int qs=0;qs<2;qs++)
            qf[qs] = *(const short8*)(smem + qbase + dch*4096 + ks*2048 + qs*512);
          #pragma unroll
          for (int kvsub=0;kvsub<2;kvsub++)
            #pragma unroll
            for (int qs=0;qs<2;qs++)
              sacc[kvsub][qs] = __builtin_amdgcn_mfma_f32_32x32x16_bf16(
                  kfb[bf][kvsub*4+dc2*2+ks], qf[qs], sacc[kvsub][qs], 0, 0, 0);
        }
      __builtin_amdgcn_s_setprio(0);
    }

    // prime vfb[0] early: drains under softmax + across B_RAW
    #pragma unroll
    for (int dsub=0;dsub<2;dsub++)
      #pragma unroll
      for (int ts=0;ts<4;ts++)
        vfb[0][dsub*4+ts] = *(const short8*)(vbase + (size_t)dsub*32768 + ts*1024);

    // ================= softmax: p = 2^s (raw v_exp_f32; scale cancels) =====
    #pragma unroll
    for (int kvsub=0;kvsub<2;kvsub++)
      #pragma unroll
      for (int qs=0;qs<2;qs++){
        #pragma unroll
        for (int g4=0; g4<4; g4++){
          float p0 = fast_exp2(sacc[kvsub][qs][4*g4+0]);
          float p1 = fast_exp2(sacc[kvsub][qs][4*g4+1]);
          float p2 = fast_exp2(sacc[kvsub][qs][4*g4+2]);
          float p3 = fast_exp2(sacc[kvsub][qs][4*g4+3]);
          ls[qs] += (p0 + p1) + (p2 + p3);
          uint2 pv;
          pv.x = cvt_pk_bf16(p0, p1);
          pv.y = cvt_pk_bf16(p2, p3);
          *(uint2*)(smem + pwbase + kvsub*4096 + g4*1024 + qs*512) = pv;
        }
      }
    bar_lgkm();                                        // B_RAW: P visible (vmcnt live)

    // ================= PV phase: oacc[dsub][qs] += V^T_band x P^ ============
    #pragma unroll
    for (int g=0; g<8; g++){
      const int bf = g & 1;
      if (g < 7){
        #pragma unroll
        for (int dsub=0;dsub<2;dsub++)
          #pragma unroll
          for (int ts=0;ts<4;ts++)
            vfb[bf^1][dsub*4+ts] = *(const short8*)(vbase
                + (size_t)dsub*32768 + ((g+1)*4+ts)*1024);
      }
      __builtin_amdgcn_s_setprio(1);
      #pragma unroll
      for (int ts=0; ts<4; ts++){
        const int tst = g*4 + ts;
        short8 pf[2];
        #pragma unroll
        for (int qs=0;qs<2;qs++)
          pf[qs] = *(const short8*)(smem + prbase + tst*2048 + qs*512);
        #pragma unroll
        for (int dsub=0;dsub<2;dsub++)
          #pragma unroll
          for (int qs=0;qs<2;qs++)
            oacc[dsub][qs] = __builtin_amdgcn_mfma_f32_32x32x16_bf16(
                vfb[bf][dsub*4+ts], pf[qs], oacc[dsub][qs], 0, 0, 0);
      }
      __builtin_amdgcn_s_setprio(0);
    }

    // prime kfb[0] for tile t+1: stays in flight across B_WAR
    if (!last){
      #pragma unroll
      for (int kvsub=0;kvsub<2;kvsub++)
        #pragma unroll
        for (int dc2=0;dc2<2;dc2++)
          #pragma unroll
          for (int ks=0;ks<2;ks++)
            kfb[0][kvsub*4+dc2*2+ks] = *(const short8*)(kbaseN
                + (size_t)kvsub*32768 + dc2*2048 + ks*1024);
    }
    bar_lgkm();                                        // B_WAR: P reusable (vmcnt live)
  }

  // ---- final cross-wave l reduction (once) ----
  ls[0] += __shfl_xor(ls[0], 32);
  ls[1] += __shfl_xor(ls[1], 32);
  if (hi == 0){
    lsum_lds[w*64 + lo]      = ls[0];
    lsum_lds[w*64 + 32 + lo] = ls[1];
  }
  __syncthreads();

  // ---- epilogue: out[q][d] = O^T[d][q] / l ----
  #pragma unroll
  for (int qs=0;qs<2;qs++){
    float l_tot = 0.f;
    #pragma unroll
    for (int wv=0;wv<8;wv++) l_tot += lsum_lds[wv*64 + qs*32 + lo];
    const float inv = 1.0f / l_tot;
    const size_t row = qrow0 + qs*32 + lo;
    #pragma unroll
    for (int dsub=0;dsub<2;dsub++){
      #pragma unroll
      for (int g4=0;g4<4;g4++){
        float4v ov;
        #pragma unroll
        for (int j=0;j<4;j++) ov[j] = oacc[dsub][qs][4*g4+j]*inv;
        *(float4v*)&out[row*512 + w*64 + dsub*32 + g4*8 + hi*4] = ov;
      }
    }
  }
}

extern "C" void kernel_launch(void* const* d_in, const int* in_sizes, int n_in,
                              void* d_out, int out_size, void* d_ws, size_t ws_size,
                              hipStream_t stream)
{
  const float* m_states = (const float*)d_in[0];
  const float* f_k      = (const float*)d_in[1];
  const float* f_v      = (const float*)d_in[2];
  const float* W_q      = (const float*)d_in[3];
  const float* b_q      = (const float*)d_in[4];
  const float* W_k      = (const float*)d_in[5];
  const float* b_k      = (const float*)d_in[6];
  const float* W_v      = (const float*)d_in[7];
  const float* b_v      = (const float*)d_in[8];
  float* out = (float*)d_out;

  // workspace: WqT 1MB | WkT 0.5MB | WvT 0.5MB | Q 16MB | Kfrag 16MB | Vfrag 16MB
  char* ws = (char*)d_ws;
  short* WqT = (short*)(ws);
  short* WkT = (short*)(ws + 1048576);
  short* WvT = (short*)(ws + 1048576 + 524288);
  short* Qb  = (short*)(ws + 2097152);
  short* Kfr = Qb + (size_t)16384*512;
  short* Vfr = Kfr + (size_t)16384*512;

  transpose_cvt_fused<<<4096, 256, 0, stream>>>(W_q, W_k, W_v, WqT, WkT, WvT);

  // 1/sqrt(512) * log2(e): softmax runs in base-2 domain
  const float scale = 0.044194173824159216f * 1.4426950408889634f;
  proj_gemm_fused<<<dim3(256,3), 256, 0, stream>>>(
      m_states, f_k, f_v, WqT, WkT, WvT, b_q, b_k, b_v,
      Qb, Kfr, Vfr, scale);

  attn_fwd<<<256, 512, ALDS, stream>>>((const char*)Qb, (const char*)Kfr,
                                       (const char*)Vfr, out);
}

// Round 16
// 181.817 us; speedup vs baseline: 1.4266x; 1.0786x over previous
//
#include <hip/hip_runtime.h>

// ============================================================================
// InteractionLayer v16: S-phase in FP8 (e4m3). attn schedule = v11 VERBATIM.
//   - K workspace + Q tile in OCP fp8: per-tile VMEM 1MB -> 768KB (-25%),
//     kfb 64->32 VGPR (relieves the 4x-confirmed spill balance), Q LDS 32KB.
//   - mfma_f32_32x32x16_fp8_fp8: SAME shape/index pattern as bf16 (8 k-elems
//     per lane, 1B each) -> dtype substitution, zero schedule change.
//   - numerics: scale NOT folded into Q (keeps Q/K std ~0.58 in e4m3 sweet
//     range); softmax does p = exp2(sacc * SC), SC = log2e/sqrt(512).
//   - P, V stay bf16; PV path byte-identical to v11.
// All bf16 MFMA = v_mfma_f32_32x32x16_bf16; layouts per m74/m101.
// Liveness law (r4/r5/r12/r14): kfb and vfb must never be live together.
// ============================================================================

typedef __attribute__((ext_vector_type(8)))  short short8;
typedef __attribute__((ext_vector_type(16))) float f32x16;
typedef __attribute__((ext_vector_type(4)))  float float4v;

#define SC_QK (0.044194173824159216f * 1.4426950408889634f)

__device__ __forceinline__ short f2bf(float x){
  unsigned int u = __float_as_uint(x);
  u = (u + 0x7FFFu + ((u >> 16) & 1u)) >> 16;   // RNE f32->bf16 (finite inputs)
  return (short)u;
}

__device__ __forceinline__ unsigned cvt_pk_bf16(float a, float b){
  unsigned r;                                    // D.lo=bf16(a), D.hi=bf16(b), RNE
  asm("v_cvt_pk_bf16_f32 %0, %1, %2" : "=v"(r) : "v"(a), "v"(b));
  return r;
}

__device__ __forceinline__ unsigned char f2fp8(float x){
  int p = __builtin_amdgcn_cvt_pk_fp8_f32(x, 0.f, 0, false);  // OCP e4m3, RNE-sat
  return (unsigned char)(p & 0xFF);
}

__device__ __forceinline__ float fast_exp2(float x){
  float r; asm("v_exp_f32 %0, %1" : "=v"(r) : "v"(x)); return r;
}

// LDS-fence barrier that does NOT drain vmcnt (prefetches stay in flight)
__device__ __forceinline__ void bar_lgkm(){
  asm volatile("s_waitcnt lgkmcnt(0)" ::: "memory");
  __builtin_amdgcn_s_barrier();
}

typedef const __attribute__((address_space(1))) unsigned int guint_t;
typedef __attribute__((address_space(3))) unsigned int luint_t;
__device__ __forceinline__ void gl_lds16(const void* g, void* l){
  __builtin_amdgcn_global_load_lds((guint_t*)g, (luint_t*)l, 16, 0, 0);
}

// ---------------- fused weight transpose + bf16 convert ----------------
__global__ __launch_bounds__(256) void transpose_cvt_fused(
    const float* __restrict__ Wq, const float* __restrict__ Wk,
    const float* __restrict__ Wv,
    short* __restrict__ WqT, short* __restrict__ WkT, short* __restrict__ WvT)
{
  int idx = blockIdx.x * 256 + threadIdx.x;
  if (idx < 524288){
    int n = idx & 511, k = idx >> 9;
    WqT[(n<<10) + k] = f2bf(Wq[idx]);
  } else if (idx < 786432){
    int j = idx - 524288; int n = j & 511, k = j >> 9;
    WkT[(n<<9) + k] = f2bf(Wk[j]);
  } else {
    int j = idx - 786432; int n = j & 511, k = j >> 9;
    WvT[(n<<9) + k] = f2bf(Wv[j]);
  }
}

// ---------------- fused projection GEMM: 64x512 full-width blocks ----------
// grid (256, 3): blockIdx.x = bm (64-row panel), blockIdx.y = pz (Q/K/V).
// pz==0 (Q): fp8 attn-layout  addr = (t>>6)*32768 + (d>>3)*512 + (t&63)*8 + (d&7)
// pz==1 (K): fp8 frag-tiled   addr = (t>>9)*262144 + ((t>>5)&15)*16384
//                                  + (d>>4)*512 + ((t&31)+32*((d>>3)&1))*8 + (d&7)
// pz==2 (V): bf16 frag-tiled (unchanged from v11)
__global__ __launch_bounds__(256, 2) void proj_gemm_fused(
    const float* __restrict__ Aq, const float* __restrict__ Ak,
    const float* __restrict__ Av,
    const short* __restrict__ Wq, const short* __restrict__ Wk,
    const short* __restrict__ Wv,
    const float* __restrict__ bq, const float* __restrict__ bk,
    const float* __restrict__ bv,
    char* __restrict__ Cq, char* __restrict__ Ck, char* __restrict__ Cv)
{
  __shared__ char As[8192];     // [64 rows][64 k] bf16, 128B/row, XOR swizzle
  __shared__ char Bs[65536];    // [512 cols][64 k] bf16 (W^T rows), 128B/row
  const int pz = blockIdx.y;
  const float* A    = (pz==0) ? Aq : (pz==1) ? Ak : Av;
  const short* WT   = (pz==0) ? Wq : (pz==1) ? Wk : Wv;
  const float* bias = (pz==0) ? bq : (pz==1) ? bk : bv;
  char* Cb          = (pz==0) ? Cq : (pz==1) ? Ck : Cv;
  const int K       = (pz==0) ? 1024 : 512;

  const int tid = threadIdx.x;
  const int wid = tid >> 6, lane = tid & 63;
  const int lo = lane & 31, hi = lane >> 5;
  const int bm = blockIdx.x;
  const char* WTb = (const char*)WT;

  f32x16 acc[2][4];
  #pragma unroll
  for (int i=0;i<2;i++)
    #pragma unroll
    for (int j=0;j<4;j++)
      #pragma unroll
      for (int r=0;r<16;r++) acc[i][j][r] = 0.0f;

  const int srow = tid >> 2, sslot = tid & 3;   // A: 64 rows x 4 thr/row
  for (int k0 = 0; k0 < K; k0 += 64) {
    #pragma unroll
    for (int i=0;i<16;i++){
      const int rb0 = wid*128 + i*8;
      const int rr = lane >> 3;                  // 0..7
      const void* src = WTb + ((size_t)(rb0 + rr)*K + k0)*2
                        + (((lane&7)*16) ^ (rr<<4));
      gl_lds16(src, Bs + rb0*128);
    }
    {
      const float4v* src = (const float4v*)&A[(size_t)(bm*64+srow)*K + k0 + sslot*16];
      float4v f0 = src[0], f1 = src[1], f2 = src[2], f3 = src[3];
      uint4 u0, u1;
      u0.x = cvt_pk_bf16(f0[0], f0[1]);
      u0.y = cvt_pk_bf16(f0[2], f0[3]);
      u0.z = cvt_pk_bf16(f1[0], f1[1]);
      u0.w = cvt_pk_bf16(f1[2], f1[3]);
      u1.x = cvt_pk_bf16(f2[0], f2[1]);
      u1.y = cvt_pk_bf16(f2[2], f2[3]);
      u1.z = cvt_pk_bf16(f3[0], f3[1]);
      u1.w = cvt_pk_bf16(f3[2], f3[3]);
      const int swz = (srow&7)<<4;
      *(uint4*)(As + srow*128 + ((sslot*32)      ^ swz)) = u0;
      *(uint4*)(As + srow*128 + ((sslot*32 + 16) ^ swz)) = u1;
    }
    __syncthreads();
    #pragma unroll
    for (int dc=0; dc<4; dc++){
      short8 af[2], bfr[4];
      #pragma unroll
      for (int mt=0;mt<2;mt++){
        const int ra = mt*32+lo;
        af[mt] = *(const short8*)(As + ra*128 + ((dc*32 + hi*16) ^ ((ra&7)<<4)));
      }
      #pragma unroll
      for (int nt=0;nt<4;nt++){
        const int rb = wid*128 + nt*32 + lo;
        bfr[nt] = *(const short8*)(Bs + rb*128 + ((dc*32 + hi*16) ^ ((rb&7)<<4)));
      }
      #pragma unroll
      for (int mt=0;mt<2;mt++)
        #pragma unroll
        for (int nt=0;nt<4;nt++)
          acc[mt][nt] = __builtin_amdgcn_mfma_f32_32x32x16_bf16(af[mt], bfr[nt], acc[mt][nt], 0, 0, 0);
    }
    __syncthreads();
  }

  #pragma unroll
  for (int nt=0;nt<4;nt++){
    const int col = wid*128 + nt*32 + lo;
    const float bv2 = bias[col];
    #pragma unroll
    for (int mt=0;mt<2;mt++){
      const int grow0 = bm*64 + mt*32;
      if (pz == 0){            // Q fp8 attn-layout (unscaled; SC applied in attn)
        #pragma unroll
        for (int r=0;r<16;r++){
          const int t = grow0 + (r&3) + 8*(r>>2) + 4*hi;
          const int d = col;
          const float val = acc[mt][nt][r] + bv2;
          size_t addr = (size_t)(t>>6)*32768 + (size_t)(d>>3)*512
                      + (size_t)(t&63)*8 + (d&7);
          *(unsigned char*)(Cb + addr) = f2fp8(val);
        }
      } else if (pz == 1){     // K fp8 band-major frag-tiled
        #pragma unroll
        for (int r=0;r<16;r++){
          const int t = grow0 + (r&3) + 8*(r>>2) + 4*hi;
          const int d = col;
          const float val = acc[mt][nt][r] + bv2;
          size_t addr = (size_t)(t>>9)*262144 + (size_t)((t>>5)&15)*16384
                      + (size_t)(d>>4)*512
                      + (size_t)((t&31) + 32*((d>>3)&1))*8 + (d&7);
          *(unsigned char*)(Cb + addr) = f2fp8(val);
        }
      } else {                 // V bf16 band-major frag-tiled (unchanged)
        #pragma unroll
        for (int r=0;r<16;r++){
          const int t = grow0 + (r&3) + 8*(r>>2) + 4*hi;
          const int d = col;
          const float val = acc[mt][nt][r] + bv2;
          size_t addr = (size_t)(t>>9)*524288 + (size_t)(d>>6)*65536
                      + (size_t)(((d>>5)&1)*32 + ((t>>4)&31))*1024
                      + (size_t)((d&31) + 32*((t>>3)&1))*16 + (t&7)*2;
          *(short*)(Cb + addr) = f2bf(val);
        }
      }
    }
  }
}

// ---------------- fused flash attention v16: fp8 S-phase, v11 schedule -----
#define PLDS  32768
#define LSUMO 98304
#define ALDS  100352

__global__ __launch_bounds__(512, 2) void attn_fwd(
    const char* __restrict__ Qg, const char* __restrict__ Kf,
    const char* __restrict__ Vf, float* __restrict__ out)
{
  extern __shared__ char smem[];
  float* lsum_lds = (float*)(smem + LSUMO);

  const int tid = threadIdx.x;
  const int w = tid >> 6, lane = tid & 63;
  const int lo = lane & 31, hi = lane >> 5;
  const int wg = ((blockIdx.x & 7) << 5) + (blockIdx.x >> 3);  // XCD swizzle
  const int b = wg >> 6, qt = wg & 63;
  const size_t qrow0 = ((size_t)b << 12) + (size_t)qt*64;

  // per-lane LDS bases
  const int qbase  = hi*512 + lo*8;                   // Q reads (fp8, ds_read_b64)
  const int prbase = PLDS + hi*1024 + lo*16;          // P reads (bf16)
  const int pwbase = PLDS + (w<<13) + lo*16 + hi*8;   // P writes

  // ---- prologue: stage Q (fp8 attn layout, 32KB) -- contiguous gl_lds ----
  {
    const char* qsrc = Qg + (size_t)wg*32768;
    #pragma unroll
    for (int i=0;i<4;i++)
      gl_lds16(qsrc + (w*4+i)*1024 + lane*16, smem + (w*4+i)*1024);
  }

  f32x16 oacc[2][2];
  #pragma unroll
  for (int i=0;i<2;i++)
    #pragma unroll
    for (int j=0;j<2;j++)
      #pragma unroll
      for (int r=0;r<16;r++) oacc[i][j][r]=0.f;
  float ls[2] = {0.f, 0.f};

  const char* Kb = Kf + (size_t)b*2097152;            // fp8: 2MB/batch
  const char* Vb = Vf + (size_t)b*4194304;            // bf16: 4MB/batch
  long   kfb[2][8];                                   // fp8 frags: 8B each
  short8 vfb[2][8];                                   // bf16 frags: 16B each

  // prime kfb[0] for tile 0 (drained by the prologue __syncthreads, once)
  {
    const char* kbase0 = Kb + (size_t)(2*w)*16384 + (size_t)lane*8;
    #pragma unroll
    for (int kvsub=0;kvsub<2;kvsub++)
      #pragma unroll
      for (int dc2=0;dc2<2;dc2++)
        #pragma unroll
        for (int ks=0;ks<2;ks++)
          kfb[0][kvsub*4+dc2*2+ks] = *(const long*)(kbase0
              + (size_t)kvsub*16384 + dc2*1024 + ks*512);
  }
  __syncthreads();   // full drain: Q staging (gl_lds) must be LDS-visible

  for (int kvt = 0; kvt < 8; kvt++) {
    const bool last = (kvt == 7);
    const char* kbaseC = Kb + (size_t)kvt*262144 + (size_t)(2*w)*16384 + (size_t)lane*8;
    const char* kbaseN = Kb + (size_t)((kvt+1)&7)*262144 + (size_t)(2*w)*16384 + (size_t)lane*8;
    const char* vbase  = Vb + (size_t)kvt*524288 + (size_t)(w)*65536 + (size_t)lane*16;

    // ================= S phase: sacc[kvsub][qs] = K_band x Q (fp8) ==========
    f32x16 sacc[2][2];
    #pragma unroll
    for (int i=0;i<2;i++)
      #pragma unroll
      for (int j=0;j<2;j++)
        #pragma unroll
        for (int r=0;r<16;r++) sacc[i][j][r]=0.f;

    #pragma unroll
    for (int g=0; g<8; g++){
      const int bf = g & 1;
      if (g < 7){
        #pragma unroll
        for (int kvsub=0;kvsub<2;kvsub++)
          #pragma unroll
          for (int dc2=0;dc2<2;dc2++)
            #pragma unroll
            for (int ks=0;ks<2;ks++)
              kfb[bf^1][kvsub*4+dc2*2+ks] = *(const long*)(kbaseC
                  + (size_t)kvsub*16384 + (2*(g+1)+dc2)*1024 + ks*512);
      }
      __builtin_amdgcn_s_setprio(1);
      #pragma unroll
      for (int dc2=0;dc2<2;dc2++)
        #pragma unroll
        for (int ks=0;ks<2;ks++){
          const int dch = 2*g + dc2;
          long qf[2];
          #pragma unroll
          for (int qs=0;qs<2;qs++)
            qf[qs] = *(const long*)(smem + qbase + dch*2048 + ks*1024 + qs*256);
          #pragma unroll
          for (int kvsub=0;kvsub<2;kvsub++)
            #pragma unroll
            for (int qs=0;qs<2;qs++)
              sacc[kvsub][qs] = __builtin_amdgcn_mfma_f32_32x32x16_fp8_fp8(
                  kfb[bf][kvsub*4+dc2*2+ks], qf[qs], sacc[kvsub][qs], 0, 0, 0);
        }
      __builtin_amdgcn_s_setprio(0);
    }

    // prime vfb[0] early: drains under softmax + across B_RAW
    #pragma unroll
    for (int dsub=0;dsub<2;dsub++)
      #pragma unroll
      for (int ts=0;ts<4;ts++)
        vfb[0][dsub*4+ts] = *(const short8*)(vbase + (size_t)dsub*32768 + ts*1024);

    // ============ softmax: p = 2^(s*SC) (raw v_exp_f32; fixed-max) =========
    #pragma unroll
    for (int kvsub=0;kvsub<2;kvsub++)
      #pragma unroll
      for (int qs=0;qs<2;qs++){
        #pragma unroll
        for (int g4=0; g4<4; g4++){
          float p0 = fast_exp2(sacc[kvsub][qs][4*g4+0] * SC_QK);
          float p1 = fast_exp2(sacc[kvsub][qs][4*g4+1] * SC_QK);
          float p2 = fast_exp2(sacc[kvsub][qs][4*g4+2] * SC_QK);
          float p3 = fast_exp2(sacc[kvsub][qs][4*g4+3] * SC_QK);
          ls[qs] += (p0 + p1) + (p2 + p3);
          uint2 pv;
          pv.x = cvt_pk_bf16(p0, p1);
          pv.y = cvt_pk_bf16(p2, p3);
          *(uint2*)(smem + pwbase + kvsub*4096 + g4*1024 + qs*512) = pv;
        }
      }
    bar_lgkm();                                        // B_RAW: P visible (vmcnt live)

    // ================= PV phase: oacc[dsub][qs] += V^T_band x P^ ============
    #pragma unroll
    for (int g=0; g<8; g++){
      const int bf = g & 1;
      if (g < 7){
        #pragma unroll
        for (int dsub=0;dsub<2;dsub++)
          #pragma unroll
          for (int ts=0;ts<4;ts++)
            vfb[bf^1][dsub*4+ts] = *(const short8*)(vbase
                + (size_t)dsub*32768 + ((g+1)*4+ts)*1024);
      }
      __builtin_amdgcn_s_setprio(1);
      #pragma unroll
      for (int ts=0; ts<4; ts++){
        const int tst = g*4 + ts;
        short8 pf[2];
        #pragma unroll
        for (int qs=0;qs<2;qs++)
          pf[qs] = *(const short8*)(smem + prbase + tst*2048 + qs*512);
        #pragma unroll
        for (int dsub=0;dsub<2;dsub++)
          #pragma unroll
          for (int qs=0;qs<2;qs++)
            oacc[dsub][qs] = __builtin_amdgcn_mfma_f32_32x32x16_bf16(
                vfb[bf][dsub*4+ts], pf[qs], oacc[dsub][qs], 0, 0, 0);
      }
      __builtin_amdgcn_s_setprio(0);
    }

    // prime kfb[0] for tile t+1: stays in flight across B_WAR
    if (!last){
      #pragma unroll
      for (int kvsub=0;kvsub<2;kvsub++)
        #pragma unroll
        for (int dc2=0;dc2<2;dc2++)
          #pragma unroll
          for (int ks=0;ks<2;ks++)
            kfb[0][kvsub*4+dc2*2+ks] = *(const long*)(kbaseN
                + (size_t)kvsub*16384 + dc2*1024 + ks*512);
    }
    bar_lgkm();                                        // B_WAR: P reusable (vmcnt live)
  }

  // ---- final cross-wave l reduction (once) ----
  ls[0] += __shfl_xor(ls[0], 32);
  ls[1] += __shfl_xor(ls[1], 32);
  if (hi == 0){
    lsum_lds[w*64 + lo]      = ls[0];
    lsum_lds[w*64 + 32 + lo] = ls[1];
  }
  __syncthreads();

  // ---- epilogue: out[q][d] = O^T[d][q] / l ----
  #pragma unroll
  for (int qs=0;qs<2;qs++){
    float l_tot = 0.f;
    #pragma unroll
    for (int wv=0;wv<8;wv++) l_tot += lsum_lds[wv*64 + qs*32 + lo];
    const float inv = 1.0f / l_tot;
    const size_t row = qrow0 + qs*32 + lo;
    #pragma unroll
    for (int dsub=0;dsub<2;dsub++){
      #pragma unroll
      for (int g4=0;g4<4;g4++){
        float4v ov;
        #pragma unroll
        for (int j=0;j<4;j++) ov[j] = oacc[dsub][qs][4*g4+j]*inv;
        *(float4v*)&out[row*512 + w*64 + dsub*32 + g4*8 + hi*4] = ov;
      }
    }
  }
}

extern "C" void kernel_launch(void* const* d_in, const int* in_sizes, int n_in,
                              void* d_out, int out_size, void* d_ws, size_t ws_size,
                              hipStream_t stream)
{
  const float* m_states = (const float*)d_in[0];
  const float* f_k      = (const float*)d_in[1];
  const float* f_v      = (const float*)d_in[2];
  const float* W_q      = (const float*)d_in[3];
  const float* b_q      = (const float*)d_in[4];
  const float* W_k      = (const float*)d_in[5];
  const float* b_k      = (const float*)d_in[6];
  const float* W_v      = (const float*)d_in[7];
  const float* b_v      = (const float*)d_in[8];
  float* out = (float*)d_out;

  // workspace: WqT 1MB | WkT 0.5MB | WvT 0.5MB | Q fp8 8MB | K fp8 8MB | V bf16 16MB
  char* ws = (char*)d_ws;
  short* WqT = (short*)(ws);
  short* WkT = (short*)(ws + 1048576);
  short* WvT = (short*)(ws + 1048576 + 524288);
  char*  Qb  = ws + 2097152;
  char*  Kfr = Qb + 8388608;
  char*  Vfr = Kfr + 8388608;

  transpose_cvt_fused<<<4096, 256, 0, stream>>>(W_q, W_k, W_v, WqT, WkT, WvT);

  proj_gemm_fused<<<dim3(256,3), 256, 0, stream>>>(
      m_states, f_k, f_v, WqT, WkT, WvT, b_q, b_k, b_v,
      Qb, Kfr, Vfr);

  attn_fwd<<<256, 512, ALDS, stream>>>(Qb, Kfr, Vfr, out);
}

// Round 18
// 178.372 us; speedup vs baseline: 1.4541x; 1.0193x over previous
//
#include <hip/hip_runtime.h>

// ============================================================================
// InteractionLayer v18: v16 (fp8 S-phase, bf16 PV -- the proven accuracy
// frontier, 181.8us) + SINGLE-BARRIER tiles via P double-buffer in LDS.
//   - P bf16 dbuf: buf(t&1) at PLDS + (t&1)*65536; LDS = 32K Q + 128K P
//     = 163840 B (AITER fmha precedent: 160KB-LDS kernels launch on gfx950).
//   - ONE bar_lgkm per tile (B_RAW). WAR on buf(t&1) fenced by B_RAW(t+1)
//     by induction (every wave's PV(t) precedes its arrival at B_RAW(t+1)).
//   - PV(t) + S(t+1) = 256 barrier-free MFMAs; kfb(t+1) prime issued at end
//     of PV drains into S(t+1) with no barrier wait.
//   - lsum reuses the dead Q area after the loop (Q's last read precedes
//     B_RAW(7) which precedes any epilogue write).
//   - registers identical to v16; kfb/vfb liveness disjoint (law upheld).
// fp8 PV REJECTED (r17): P-fp8+V-fp8 -> absmax 2.08e-3 > 1.52e-3; even one
// alone back-solves to ~1.56e-3. PV operands must stay bf16.
// ============================================================================

typedef __attribute__((ext_vector_type(8)))  short short8;
typedef __attribute__((ext_vector_type(16))) float f32x16;
typedef __attribute__((ext_vector_type(4)))  float float4v;

#define SC_QK (0.044194173824159216f * 1.4426950408889634f)

__device__ __forceinline__ short f2bf(float x){
  unsigned int u = __float_as_uint(x);
  u = (u + 0x7FFFu + ((u >> 16) & 1u)) >> 16;   // RNE f32->bf16 (finite inputs)
  return (short)u;
}

__device__ __forceinline__ unsigned cvt_pk_bf16(float a, float b){
  unsigned r;
  asm("v_cvt_pk_bf16_f32 %0, %1, %2" : "=v"(r) : "v"(a), "v"(b));
  return r;
}

__device__ __forceinline__ unsigned char f2fp8(float x){
  int p = __builtin_amdgcn_cvt_pk_fp8_f32(x, 0.f, 0, false);  // OCP e4m3
  return (unsigned char)(p & 0xFF);
}

__device__ __forceinline__ float fast_exp2(float x){
  float r; asm("v_exp_f32 %0, %1" : "=v"(r) : "v"(x)); return r;
}

// LDS-fence barrier that does NOT drain vmcnt (prefetches stay in flight)
__device__ __forceinline__ void bar_lgkm(){
  asm volatile("s_waitcnt lgkmcnt(0)" ::: "memory");
  __builtin_amdgcn_s_barrier();
}

typedef const __attribute__((address_space(1))) unsigned int guint_t;
typedef __attribute__((address_space(3))) unsigned int luint_t;
__device__ __forceinline__ void gl_lds16(const void* g, void* l){
  __builtin_amdgcn_global_load_lds((guint_t*)g, (luint_t*)l, 16, 0, 0);
}

// ---------------- fused weight transpose + bf16 convert ----------------
__global__ __launch_bounds__(256) void transpose_cvt_fused(
    const float* __restrict__ Wq, const float* __restrict__ Wk,
    const float* __restrict__ Wv,
    short* __restrict__ WqT, short* __restrict__ WkT, short* __restrict__ WvT)
{
  int idx = blockIdx.x * 256 + threadIdx.x;
  if (idx < 524288){
    int n = idx & 511, k = idx >> 9;
    WqT[(n<<10) + k] = f2bf(Wq[idx]);
  } else if (idx < 786432){
    int j = idx - 524288; int n = j & 511, k = j >> 9;
    WkT[(n<<9) + k] = f2bf(Wk[j]);
  } else {
    int j = idx - 786432; int n = j & 511, k = j >> 9;
    WvT[(n<<9) + k] = f2bf(Wv[j]);
  }
}

// ---------------- fused projection GEMM: 64x512 full-width blocks ----------
// pz==0 (Q): fp8 attn-layout  addr = (t>>6)*32768 + (d>>3)*512 + (t&63)*8 + (d&7)
// pz==1 (K): fp8 frag-tiled   addr = (t>>9)*262144 + ((t>>5)&15)*16384
//                                  + (d>>4)*512 + ((t&31)+32*((d>>3)&1))*8 + (d&7)
// pz==2 (V): bf16 frag-tiled (v11/v16 formula)
__global__ __launch_bounds__(256, 2) void proj_gemm_fused(
    const float* __restrict__ Aq, const float* __restrict__ Ak,
    const float* __restrict__ Av,
    const short* __restrict__ Wq, const short* __restrict__ Wk,
    const short* __restrict__ Wv,
    const float* __restrict__ bq, const float* __restrict__ bk,
    const float* __restrict__ bv,
    char* __restrict__ Cq, char* __restrict__ Ck, char* __restrict__ Cv)
{
  __shared__ char As[8192];
  __shared__ char Bs[65536];
  const int pz = blockIdx.y;
  const float* A    = (pz==0) ? Aq : (pz==1) ? Ak : Av;
  const short* WT   = (pz==0) ? Wq : (pz==1) ? Wk : Wv;
  const float* bias = (pz==0) ? bq : (pz==1) ? bk : bv;
  char* Cb          = (pz==0) ? Cq : (pz==1) ? Ck : Cv;
  const int K       = (pz==0) ? 1024 : 512;

  const int tid = threadIdx.x;
  const int wid = tid >> 6, lane = tid & 63;
  const int lo = lane & 31, hi = lane >> 5;
  const int bm = blockIdx.x;
  const char* WTb = (const char*)WT;

  f32x16 acc[2][4];
  #pragma unroll
  for (int i=0;i<2;i++)
    #pragma unroll
    for (int j=0;j<4;j++)
      #pragma unroll
      for (int r=0;r<16;r++) acc[i][j][r] = 0.0f;

  const int srow = tid >> 2, sslot = tid & 3;
  for (int k0 = 0; k0 < K; k0 += 64) {
    #pragma unroll
    for (int i=0;i<16;i++){
      const int rb0 = wid*128 + i*8;
      const int rr = lane >> 3;
      const void* src = WTb + ((size_t)(rb0 + rr)*K + k0)*2
                        + (((lane&7)*16) ^ (rr<<4));
      gl_lds16(src, Bs + rb0*128);
    }
    {
      const float4v* src = (const float4v*)&A[(size_t)(bm*64+srow)*K + k0 + sslot*16];
      float4v f0 = src[0], f1 = src[1], f2 = src[2], f3 = src[3];
      uint4 u0, u1;
      u0.x = cvt_pk_bf16(f0[0], f0[1]);
      u0.y = cvt_pk_bf16(f0[2], f0[3]);
      u0.z = cvt_pk_bf16(f1[0], f1[1]);
      u0.w = cvt_pk_bf16(f1[2], f1[3]);
      u1.x = cvt_pk_bf16(f2[0], f2[1]);
      u1.y = cvt_pk_bf16(f2[2], f2[3]);
      u1.z = cvt_pk_bf16(f3[0], f3[1]);
      u1.w = cvt_pk_bf16(f3[2], f3[3]);
      const int swz = (srow&7)<<4;
      *(uint4*)(As + srow*128 + ((sslot*32)      ^ swz)) = u0;
      *(uint4*)(As + srow*128 + ((sslot*32 + 16) ^ swz)) = u1;
    }
    __syncthreads();
    #pragma unroll
    for (int dc=0; dc<4; dc++){
      short8 af[2], bfr[4];
      #pragma unroll
      for (int mt=0;mt<2;mt++){
        const int ra = mt*32+lo;
        af[mt] = *(const short8*)(As + ra*128 + ((dc*32 + hi*16) ^ ((ra&7)<<4)));
      }
      #pragma unroll
      for (int nt=0;nt<4;nt++){
        const int rb = wid*128 + nt*32 + lo;
        bfr[nt] = *(const short8*)(Bs + rb*128 + ((dc*32 + hi*16) ^ ((rb&7)<<4)));
      }
      #pragma unroll
      for (int mt=0;mt<2;mt++)
        #pragma unroll
        for (int nt=0;nt<4;nt++)
          acc[mt][nt] = __builtin_amdgcn_mfma_f32_32x32x16_bf16(af[mt], bfr[nt], acc[mt][nt], 0, 0, 0);
    }
    __syncthreads();
  }

  #pragma unroll
  for (int nt=0;nt<4;nt++){
    const int col = wid*128 + nt*32 + lo;
    const float bv2 = bias[col];
    #pragma unroll
    for (int mt=0;mt<2;mt++){
      const int grow0 = bm*64 + mt*32;
      if (pz == 0){            // Q fp8 attn-layout (unscaled; SC applied in attn)
        #pragma unroll
        for (int r=0;r<16;r++){
          const int t = grow0 + (r&3) + 8*(r>>2) + 4*hi;
          const int d = col;
          const float val = acc[mt][nt][r] + bv2;
          size_t addr = (size_t)(t>>6)*32768 + (size_t)(d>>3)*512
                      + (size_t)(t&63)*8 + (d&7);
          *(unsigned char*)(Cb + addr) = f2fp8(val);
        }
      } else if (pz == 1){     // K fp8 band-major frag-tiled
        #pragma unroll
        for (int r=0;r<16;r++){
          const int t = grow0 + (r&3) + 8*(r>>2) + 4*hi;
          const int d = col;
          const float val = acc[mt][nt][r] + bv2;
          size_t addr = (size_t)(t>>9)*262144 + (size_t)((t>>5)&15)*16384
                      + (size_t)(d>>4)*512
                      + (size_t)((t&31) + 32*((d>>3)&1))*8 + (d&7);
          *(unsigned char*)(Cb + addr) = f2fp8(val);
        }
      } else {                 // V bf16 band-major frag-tiled
        #pragma unroll
        for (int r=0;r<16;r++){
          const int t = grow0 + (r&3) + 8*(r>>2) + 4*hi;
          const int d = col;
          const float val = acc[mt][nt][r] + bv2;
          size_t addr = (size_t)(t>>9)*524288 + (size_t)(d>>6)*65536
                      + (size_t)(((d>>5)&1)*32 + ((t>>4)&31))*1024
                      + (size_t)((d&31) + 32*((t>>3)&1))*16 + (t&7)*2;
          *(short*)(Cb + addr) = f2bf(val);
        }
      }
    }
  }
}

// ------- fused flash attention v18: fp8 S, bf16 PV, P dbuf, 1 barrier ------
#define PLDS  32768
#define ALDS  163840

__global__ __launch_bounds__(512, 2) void attn_fwd(
    const char* __restrict__ Qg, const char* __restrict__ Kf,
    const char* __restrict__ Vf, float* __restrict__ out)
{
  extern __shared__ char smem[];
  float* lsum_lds = (float*)smem;                     // reuses Q area post-loop

  const int tid = threadIdx.x;
  const int w = tid >> 6, lane = tid & 63;
  const int lo = lane & 31, hi = lane >> 5;
  const int wg = ((blockIdx.x & 7) << 5) + (blockIdx.x >> 3);  // XCD swizzle
  const int b = wg >> 6, qt = wg & 63;
  const size_t qrow0 = ((size_t)b << 12) + (size_t)qt*64;

  // per-lane LDS bases
  const int qbase  = hi*512 + lo*8;                   // Q reads (fp8 b64)
  const int prbase = PLDS + hi*1024 + lo*16;          // P reads (bf16)
  const int pwbase = PLDS + (w<<13) + lo*16 + hi*8;   // P writes

  // ---- prologue: stage Q (fp8 attn layout, 32KB) -- contiguous gl_lds ----
  {
    const char* qsrc = Qg + (size_t)wg*32768;
    #pragma unroll
    for (int i=0;i<4;i++)
      gl_lds16(qsrc + (w*4+i)*1024 + lane*16, smem + (w*4+i)*1024);
  }

  f32x16 oacc[2][2];
  #pragma unroll
  for (int i=0;i<2;i++)
    #pragma unroll
    for (int j=0;j<2;j++)
      #pragma unroll
      for (int r=0;r<16;r++) oacc[i][j][r]=0.f;
  float ls[2] = {0.f, 0.f};

  const char* Kb = Kf + (size_t)b*2097152;            // fp8: 2MB/batch
  const char* Vb = Vf + (size_t)b*4194304;            // bf16: 4MB/batch
  long   kfb[2][8];                                   // fp8 frags: 8B each
  short8 vfb[2][8];                                   // bf16 frags: 16B each

  // prime kfb[0] for tile 0 (drained by the prologue __syncthreads, once)
  {
    const char* kbase0 = Kb + (size_t)(2*w)*16384 + (size_t)lane*8;
    #pragma unroll
    for (int kvsub=0;kvsub<2;kvsub++)
      #pragma unroll
      for (int dc2=0;dc2<2;dc2++)
        #pragma unroll
        for (int ks=0;ks<2;ks++)
          kfb[0][kvsub*4+dc2*2+ks] = *(const long*)(kbase0
              + (size_t)kvsub*16384 + dc2*1024 + ks*512);
  }
  __syncthreads();   // full drain: Q staging (gl_lds) must be LDS-visible

  for (int kvt = 0; kvt < 8; kvt++) {
    const bool last = (kvt == 7);
    const char* kbaseC = Kb + (size_t)kvt*262144 + (size_t)(2*w)*16384 + (size_t)lane*8;
    const char* kbaseN = Kb + (size_t)((kvt+1)&7)*262144 + (size_t)(2*w)*16384 + (size_t)lane*8;
    const char* vbase  = Vb + (size_t)kvt*524288 + (size_t)(w)*65536 + (size_t)lane*16;
    const int pb = (kvt & 1) << 16;                   // P buffer select

    // ================= S phase: sacc[kvsub][qs] = K_band x Q (fp8) ==========
    f32x16 sacc[2][2];
    #pragma unroll
    for (int i=0;i<2;i++)
      #pragma unroll
      for (int j=0;j<2;j++)
        #pragma unroll
        for (int r=0;r<16;r++) sacc[i][j][r]=0.f;

    #pragma unroll
    for (int g=0; g<8; g++){
      const int bf = g & 1;
      if (g < 7){
        #pragma unroll
        for (int kvsub=0;kvsub<2;kvsub++)
          #pragma unroll
          for (int dc2=0;dc2<2;dc2++)
            #pragma unroll
            for (int ks=0;ks<2;ks++)
              kfb[bf^1][kvsub*4+dc2*2+ks] = *(const long*)(kbaseC
                  + (size_t)kvsub*16384 + (2*(g+1)+dc2)*1024 + ks*512);
      }
      __builtin_amdgcn_s_setprio(1);
      #pragma unroll
      for (int dc2=0;dc2<2;dc2++)
        #pragma unroll
        for (int ks=0;ks<2;ks++){
          const int dch = 2*g + dc2;
          long qf[2];
          #pragma unroll
          for (int qs=0;qs<2;qs++)
            qf[qs] = *(const long*)(smem + qbase + dch*2048 + ks*1024 + qs*256);
          #pragma unroll
          for (int kvsub=0;kvsub<2;kvsub++)
            #pragma unroll
            for (int qs=0;qs<2;qs++)
              sacc[kvsub][qs] = __builtin_amdgcn_mfma_f32_32x32x16_fp8_fp8(
                  kfb[bf][kvsub*4+dc2*2+ks], qf[qs], sacc[kvsub][qs], 0, 0, 0);
        }
      __builtin_amdgcn_s_setprio(0);
    }

    // prime vfb[0] early: drains under softmax + across B_RAW
    #pragma unroll
    for (int dsub=0;dsub<2;dsub++)
      #pragma unroll
      for (int ts=0;ts<4;ts++)
        vfb[0][dsub*4+ts] = *(const short8*)(vbase + (size_t)dsub*32768 + ts*1024);

    // ====== softmax: p = 2^(s*SC) -> P bf16 into buf(t&1) ==================
    #pragma unroll
    for (int kvsub=0;kvsub<2;kvsub++)
      #pragma unroll
      for (int qs=0;qs<2;qs++){
        #pragma unroll
        for (int g4=0; g4<4; g4++){
          float p0 = fast_exp2(sacc[kvsub][qs][4*g4+0] * SC_QK);
          float p1 = fast_exp2(sacc[kvsub][qs][4*g4+1] * SC_QK);
          float p2 = fast_exp2(sacc[kvsub][qs][4*g4+2] * SC_QK);
          float p3 = fast_exp2(sacc[kvsub][qs][4*g4+3] * SC_QK);
          ls[qs] += (p0 + p1) + (p2 + p3);
          uint2 pv;
          pv.x = cvt_pk_bf16(p0, p1);
          pv.y = cvt_pk_bf16(p2, p3);
          *(uint2*)(smem + pb + pwbase + kvsub*4096 + g4*1024 + qs*512) = pv;
        }
      }
    bar_lgkm();   // B_RAW: the ONLY barrier per tile. WAR on buf(t&1) is
                  // fenced by B_RAW(t+1) by induction.

    // ============ PV phase (bf16): oacc[dsub][qs] += V^T_band x P^ ==========
    #pragma unroll
    for (int g=0; g<8; g++){
      const int bf = g & 1;
      if (g < 7){
        #pragma unroll
        for (int dsub=0;dsub<2;dsub++)
          #pragma unroll
          for (int ts=0;ts<4;ts++)
            vfb[bf^1][dsub*4+ts] = *(const short8*)(vbase
                + (size_t)dsub*32768 + ((g+1)*4+ts)*1024);
      }
      __builtin_amdgcn_s_setprio(1);
      #pragma unroll
      for (int ts=0; ts<4; ts++){
        const int tst = g*4 + ts;
        short8 pf[2];
        #pragma unroll
        for (int qs=0;qs<2;qs++)
          pf[qs] = *(const short8*)(smem + pb + prbase + tst*2048 + qs*512);
        #pragma unroll
        for (int dsub=0;dsub<2;dsub++)
          #pragma unroll
          for (int qs=0;qs<2;qs++)
            oacc[dsub][qs] = __builtin_amdgcn_mfma_f32_32x32x16_bf16(
                vfb[bf][dsub*4+ts], pf[qs], oacc[dsub][qs], 0, 0, 0);
      }
      __builtin_amdgcn_s_setprio(0);
    }

    // prime kfb[0] for tile t+1: flows straight into S(t+1), no barrier wait
    if (!last){
      #pragma unroll
      for (int kvsub=0;kvsub<2;kvsub++)
        #pragma unroll
        for (int dc2=0;dc2<2;dc2++)
          #pragma unroll
          for (int ks=0;ks<2;ks++)
            kfb[0][kvsub*4+dc2*2+ks] = *(const long*)(kbaseN
                + (size_t)kvsub*16384 + dc2*1024 + ks*512);
    }
  }

  // ---- final cross-wave l reduction (Q area is dead: last Q read precedes
  // B_RAW(7), which precedes every wave's arrival here) ----
  ls[0] += __shfl_xor(ls[0], 32);
  ls[1] += __shfl_xor(ls[1], 32);
  if (hi == 0){
    lsum_lds[w*64 + lo]      = ls[0];
    lsum_lds[w*64 + 32 + lo] = ls[1];
  }
  __syncthreads();

  // ---- epilogue: out[q][d] = O^T[d][q] / l ----
  #pragma unroll
  for (int qs=0;qs<2;qs++){
    float l_tot = 0.f;
    #pragma unroll
    for (int wv=0;wv<8;wv++) l_tot += lsum_lds[wv*64 + qs*32 + lo];
    const float inv = 1.0f / l_tot;
    const size_t row = qrow0 + qs*32 + lo;
    #pragma unroll
    for (int dsub=0;dsub<2;dsub++){
      #pragma unroll
      for (int g4=0;g4<4;g4++){
        float4v ov;
        #pragma unroll
        for (int j=0;j<4;j++) ov[j] = oacc[dsub][qs][4*g4+j]*inv;
        *(float4v*)&out[row*512 + w*64 + dsub*32 + g4*8 + hi*4] = ov;
      }
    }
  }
}

extern "C" void kernel_launch(void* const* d_in, const int* in_sizes, int n_in,
                              void* d_out, int out_size, void* d_ws, size_t ws_size,
                              hipStream_t stream)
{
  const float* m_states = (const float*)d_in[0];
  const float* f_k      = (const float*)d_in[1];
  const float* f_v      = (const float*)d_in[2];
  const float* W_q      = (const float*)d_in[3];
  const float* b_q      = (const float*)d_in[4];
  const float* W_k      = (const float*)d_in[5];
  const float* b_k      = (const float*)d_in[6];
  const float* W_v      = (const float*)d_in[7];
  const float* b_v      = (const float*)d_in[8];
  float* out = (float*)d_out;

  // workspace: WqT 1MB | WkT 0.5MB | WvT 0.5MB | Q fp8 8MB | K fp8 8MB | V bf16 16MB
  char* ws = (char*)d_ws;
  short* WqT = (short*)(ws);
  short* WkT = (short*)(ws + 1048576);
  short* WvT = (short*)(ws + 1048576 + 524288);
  char*  Qb  = ws + 2097152;
  char*  Kfr = Qb + 8388608;
  char*  Vfr = Kfr + 8388608;

  transpose_cvt_fused<<<4096, 256, 0, stream>>>(W_q, W_k, W_v, WqT, WkT, WvT);

  proj_gemm_fused<<<dim3(256,3), 256, 0, stream>>>(
      m_states, f_k, f_v, WqT, WkT, WvT, b_q, b_k, b_v,
      Qb, Kfr, Vfr);

  attn_fwd<<<256, 512, ALDS, stream>>>(Qb, Kfr, Vfr, out);
}